// Round 2
// baseline (130.777 us; speedup 1.0000x reference)
//
#include <hip/hip_runtime.h>

// ISTSimulator: 131072 independent scan chains (B=65536, V=2), L=200 steps.
// One thread per chain. Register-buffered output (20 steps) flushed as
// float4 stores so HBM write traffic == exact output size (105 MB).

#if __has_builtin(__builtin_amdgcn_exp2f)
#define FAST_EXP2(x) __builtin_amdgcn_exp2f(x)
#else
#define FAST_EXP2(x) exp2f(x)
#endif
#if __has_builtin(__builtin_amdgcn_logf)
#define FAST_LOG2(x) __builtin_amdgcn_logf(x)  // v_log_f32 = log2(x)
#else
#define FAST_LOG2(x) log2f(x)
#endif

namespace {
constexpr int kL = 200;
constexpr int kChunk = 20;                 // 20 floats = 80 B, 16B-aligned
constexpr int kNChunk = kL / kChunk;
constexpr float kEps = 1e-12f;
constexpr float kLog2e = 1.44269504088896340736f;
}  // namespace

__global__ __launch_bounds__(256) void ist_sim_kernel(
    const float* __restrict__ p, float* __restrict__ out) {
  const int tid = blockIdx.x * 256 + threadIdx.x;  // chain id = b*2 + v

  // params: [lam_raw, beta_raw, k_d, mu, k_f, n_c, w_t] at p[tid*7 + k]
  const float* q = p + tid * 7;
  const float lam  = 0.001f * fmaxf(q[0], 0.0f);
  const float beta = fmaf(10.0f, fmaxf(q[1], 0.0f), 1.0f);
  const float kd = q[2];
  const float mu = q[3];
  const float kf = q[4];
  const float nc = q[5];
  const float wt = q[6];

  // sigmoid arg scaled to log2 domain: x2 = ((n - nc)/wt) * log2(e)
  const float inv_wt = __builtin_amdgcn_rcpf(wt);
  const float a2 = inv_wt * kLog2e;
  const float c2 = nc * a2;

  float D = 0.0f;
  float F = kEps;
  float* o = out + (size_t)tid * kL;

  for (int ch = 0; ch < kNChunk; ++ch) {
    float buf[kChunk];
#pragma unroll
    for (int i = 0; i < kChunk; ++i) {
      const float nf = (float)(ch * kChunk + i);

      // D update: D += lam * (1-D)^beta, clipped. (1.0f-1e-12f == 1.0f in f32,
      // identical to the jax reference's weak-typed clip constant.)
      const float om = fmaxf(1.0f - D, kEps);
      const float t = beta * FAST_LOG2(om);
      D = fminf(fmaf(lam, FAST_EXP2(t), D), 1.0f);

      // gate: g = sigmoid((n - nc)/wt) = 1/(1 + 2^(-x2))
      const float x2 = fmaf(nf, a2, -c2);
      const float e = FAST_EXP2(-x2);
      const float g = __builtin_amdgcn_rcpf(1.0f + e);

      // F update: F = clip((1 + mu*g)*F + eps*g, 0, 1)
      float v = fmaf(mu * g, F, F);
      v = fmaf(kEps, g, v);
      F = fminf(fmaxf(v, 0.0f), 1.0f);

      buf[i] = fmaf(kd, D, kf * F);
    }
    // flush 20 results as 5 x float4 (16B aligned: tid*800 + ch*80)
    float4* dst = reinterpret_cast<float4*>(o + ch * kChunk);
#pragma unroll
    for (int j = 0; j < kChunk / 4; ++j) {
      dst[j] = make_float4(buf[4 * j], buf[4 * j + 1], buf[4 * j + 2],
                           buf[4 * j + 3]);
    }
  }
}

extern "C" void kernel_launch(void* const* d_in, const int* in_sizes, int n_in,
                              void* d_out, int out_size, void* d_ws,
                              size_t ws_size, hipStream_t stream) {
  const float* p = (const float*)d_in[0];
  float* out = (float*)d_out;
  const int total_chains = 65536 * 2;  // B * NUM_VARS
  ist_sim_kernel<<<total_chains / 256, 256, 0, stream>>>(p, out);
}

// Round 3
// 124.739 us; speedup vs baseline: 1.0484x; 1.0484x over previous
//
#include <hip/hip_runtime.h>

// ISTSimulator: 131072 independent scan chains (B=65536, V=2), L=200 steps.
// One thread per chain. All 200 outputs held in registers; flushed at the end
// through an LDS transpose (4 wave-passes) so global stores are fully
// coalesced, full-line writes (no partial-line RMW, no 16B scatter).

#if __has_builtin(__builtin_amdgcn_exp2f)
#define FAST_EXP2(x) __builtin_amdgcn_exp2f(x)
#else
#define FAST_EXP2(x) exp2f(x)
#endif
#if __has_builtin(__builtin_amdgcn_logf)
#define FAST_LOG2(x) __builtin_amdgcn_logf(x)  // v_log_f32 = log2(x)
#else
#define FAST_LOG2(x) log2f(x)
#endif

namespace {
constexpr int kL = 200;
constexpr float kEps = 1e-12f;
constexpr float kLog2e = 1.44269504088896340736f;
constexpr int kRowDw = 256;  // padded LDS row stride (dwords); swizzle fits: max 2*(j^31)=254
}  // namespace

__global__ __launch_bounds__(256, 2) void ist_sim_kernel(
    const float* __restrict__ p, float* __restrict__ out) {
  __shared__ float lds[64 * kRowDw];  // 64 KB -> 2 blocks/CU (128 KB of 160)

  const int t = threadIdx.x;
  const int tid = blockIdx.x * 256 + t;  // chain id = b*2 + v

  // params: [lam_raw, beta_raw, k_d, mu, k_f, n_c, w_t] at p[tid*7 + k]
  const float* q = p + tid * 7;
  const float lam  = 0.001f * fmaxf(q[0], 0.0f);
  const float beta = fmaf(10.0f, fmaxf(q[1], 0.0f), 1.0f);
  const float kd = q[2];
  const float mu = q[3];
  const float kf = q[4];
  const float nc = q[5];
  const float wt = q[6];

  // sigmoid arg in log2 domain: x2(n) = ((n - nc)/wt) * log2(e)
  const float a2 = __builtin_amdgcn_rcpf(wt) * kLog2e;
  const float c2 = nc * a2;

  float D = 0.0f;
  float F = kEps;
  float buf[kL];  // statically indexed (fully unrolled) -> stays in VGPR/AGPR

#pragma unroll
  for (int n = 0; n < kL; ++n) {
    // D += lam * (1-D)^beta, clipped. (1.0f - 1e-12f == 1.0f in f32, same as
    // the jax reference's weak-typed clip constant.)
    const float om = fmaxf(1.0f - D, kEps);
    D = fminf(fmaf(lam, FAST_EXP2(beta * FAST_LOG2(om)), D), 1.0f);

    // g = sigmoid((n - nc)/wt) = 1 / (1 + 2^(-x2)); n is a compile-time const
    const float x2 = fmaf((float)n, a2, -c2);
    const float g = __builtin_amdgcn_rcpf(1.0f + FAST_EXP2(-x2));

    // F = clip((1 + mu*g)*F + eps*g, 0, 1)
    float v = fmaf(mu * g, F, F);
    v = fmaf(kEps, g, v);
    F = fminf(fmaxf(v, 0.0f), 1.0f);

    buf[n] = fmaf(kd, D, kf * F);
  }

  // Flush: 4 passes. Pass k: wave k writes its 64 full rows (64 x 200 f32)
  // into swizzled LDS; then all 256 threads store the 51.2 KB contiguous
  // global region [ (block*256 + 64k)*200 , +12800 ) fully coalesced.
  const int wave = t >> 6;
  const int lane = t & 63;
  for (int k = 0; k < 4; ++k) {
    __syncthreads();
    if (wave == k) {
#pragma unroll
      for (int j = 0; j < kL / 2; ++j) {
        // float2 slot j of row `lane`, XOR-swizzled to spread banks
        const int dw = lane * kRowDw + 2 * (j ^ (lane & 31));
        *reinterpret_cast<float2*>(&lds[dw]) =
            make_float2(buf[2 * j], buf[2 * j + 1]);
      }
    }
    __syncthreads();
    float* gbase = out + ((size_t)blockIdx.x * 256 + (size_t)k * 64) * kL;
    // 64 rows x 100 float2 = 6400 float2, 25 per thread, lane-consecutive.
#pragma unroll
    for (int i = 0; i < 25; ++i) {
      const int f2 = i * 256 + t;          // global float2 index in region
      const int row = f2 / 100;            // chain within the 64-group
      const int sl = f2 - row * 100;       // float2 slot within the row
      const int dw = row * kRowDw + 2 * (sl ^ (row & 31));
      const float2 val = *reinterpret_cast<const float2*>(&lds[dw]);
      *reinterpret_cast<float2*>(&gbase[(size_t)f2 * 2]) = val;
    }
  }
}

extern "C" void kernel_launch(void* const* d_in, const int* in_sizes, int n_in,
                              void* d_out, int out_size, void* d_ws,
                              size_t ws_size, hipStream_t stream) {
  const float* p = (const float*)d_in[0];
  float* out = (float*)d_out;
  const int total_chains = 65536 * 2;  // B * NUM_VARS
  ist_sim_kernel<<<total_chains / 256, 256, 0, stream>>>(p, out);
}

// Round 6
// 124.448 us; speedup vs baseline: 1.0509x; 1.0023x over previous
//
#include <hip/hip_runtime.h>

// ISTSimulator: 131072 independent scan chains (B=65536, V=2), L=200 steps.
// One thread per chain. Outputs staged per-wave in LDS in 40-step chunks
// (stride-65 padding), then flushed as coalesced float4 stores (160B runs per
// chain). Low VGPR (no spills), no __syncthreads (wave-private LDS regions).

#if __has_builtin(__builtin_amdgcn_exp2f)
#define FAST_EXP2(x) __builtin_amdgcn_exp2f(x)
#else
#define FAST_EXP2(x) exp2f(x)
#endif
#if __has_builtin(__builtin_amdgcn_logf)
#define FAST_LOG2(x) __builtin_amdgcn_logf(x)  // v_log_f32 = log2(x)
#else
#define FAST_LOG2(x) log2f(x)
#endif

namespace {
constexpr int kL = 200;
constexpr int kChunk = 40;               // steps per staged chunk (5 chunks)
constexpr int kNChunk = kL / kChunk;     // 5
constexpr int kS = 65;                   // LDS row stride in dwords (padded)
constexpr float kEps = 1e-12f;
constexpr float kLog2e = 1.44269504088896340736f;
}  // namespace

__global__ __launch_bounds__(256) void ist_sim_kernel(
    const float* __restrict__ p, float* __restrict__ out) {
  // 4 waves * 40 steps * 65 dwords = 41.6 KB
  __shared__ float lds[4 * kChunk * kS];

  const int t = threadIdx.x;
  const int lane = t & 63;
  const int wave = t >> 6;
  float* wlds = lds + wave * kChunk * kS;

  const int tid = blockIdx.x * 256 + t;  // chain id = b*2 + v

  // params: [lam_raw, beta_raw, k_d, mu, k_f, n_c, w_t] at p[tid*7 + k]
  const float* q = p + tid * 7;
  const float lam  = 0.001f * fmaxf(q[0], 0.0f);
  const float beta = fmaf(10.0f, fmaxf(q[1], 0.0f), 1.0f);
  const float kd = q[2];
  const float mu = q[3];
  const float kf = q[4];
  const float nc = q[5];
  const float wt = q[6];

  // sigmoid arg in log2 domain: x2(n) = ((n - nc)/wt) * log2(e)
  const float a2 = __builtin_amdgcn_rcpf(wt) * kLog2e;
  const float c2 = nc * a2;

  float D = 0.0f;
  float F = kEps;

  // global base for this wave's 64-chain group (dword units)
  float* gbase =
      out + ((size_t)blockIdx.x * 256 + (size_t)wave * 64) * kL;

  for (int ch = 0; ch < kNChunk; ++ch) {
#pragma unroll
    for (int i = 0; i < kChunk; ++i) {
      const float nf = (float)(ch * kChunk + i);

      // D += lam * (1-D)^beta, clipped. (1.0f - 1e-12f == 1.0f in f32, same
      // as the jax reference's weak-typed clip constant.)
      const float om = fmaxf(1.0f - D, kEps);
      D = fminf(fmaf(lam, FAST_EXP2(beta * FAST_LOG2(om)), D), 1.0f);

      // g = sigmoid((n - nc)/wt) = 1 / (1 + 2^(-x2))
      const float x2 = fmaf(nf, a2, -c2);
      const float g = __builtin_amdgcn_rcpf(1.0f + FAST_EXP2(-x2));

      // F = clip((1 + mu*g)*F + eps*g, 0, 1)
      float v = fmaf(mu * g, F, F);
      v = fmaf(kEps, g, v);
      F = fminf(fmaxf(v, 0.0f), 1.0f);

      // stage: step i of this lane's chain. bank = (i + lane) % 32 -> 2-way.
      wlds[i * kS + lane] = fmaf(kd, D, kf * F);
    }

    // Wave-local transposed flush: 64 chains x 10 float4 (160B per chain,
    // lane-consecutive within a chain -> coalesced full-line coverage).
    // Compiler orders ds_write -> ds_read -> next-chunk ds_write via lgkmcnt.
#pragma unroll
    for (int it = 0; it < 10; ++it) {
      const int f = it * 64 + lane;   // float4 index within the wave's flush
      const int c = f / 10;           // chain within the 64-group
      const int s = f - c * 10;       // float4 slot within the 40-step chunk
      float4 v;
      v.x = wlds[(4 * s + 0) * kS + c];
      v.y = wlds[(4 * s + 1) * kS + c];
      v.z = wlds[(4 * s + 2) * kS + c];
      v.w = wlds[(4 * s + 3) * kS + c];
      *reinterpret_cast<float4*>(gbase + (size_t)c * kL + ch * kChunk +
                                 s * 4) = v;
    }
  }
}

extern "C" void kernel_launch(void* const* d_in, const int* in_sizes, int n_in,
                              void* d_out, int out_size, void* d_ws,
                              size_t ws_size, hipStream_t stream) {
  const float* p = (const float*)d_in[0];
  float* out = (float*)d_out;
  const int total_chains = 65536 * 2;  // B * NUM_VARS
  ist_sim_kernel<<<total_chains / 256, 256, 0, stream>>>(p, out);
}